// Round 11
// baseline (376.843 us; speedup 1.0000x reference)
//
#include <hip/hip_runtime.h>
#include <hip/hip_bf16.h>

typedef __attribute__((ext_vector_type(4))) float  f32x4;
typedef __attribute__((ext_vector_type(16))) float f32x16;
typedef __attribute__((ext_vector_type(8))) short  s16x8;
typedef __attribute__((ext_vector_type(4))) short  s16x4;

#define THR_  1.0e-4f   // LR * GAMMA
#define SC_   2.0e-3f   // 2 * LR

__device__ __forceinline__ unsigned short f2bf(float f) {
  union { __hip_bfloat16 b; unsigned short u; } cv;
  cv.b = __float2bfloat16(f);
  return cv.u;
}
__device__ __forceinline__ float sthr(float v) {
  return v - fmaxf(fminf(v, THR_), -THR_);   // med3 + sub
}
__device__ __forceinline__ float bflo(unsigned u) {
  return __builtin_bit_cast(float, u << 16);
}
__device__ __forceinline__ float bfhi(unsigned u) {
  return __builtin_bit_cast(float, u & 0xffff0000u);
}

// A-frag packing for 32x32x16 (A[row][k]): lane l holds row=(l&31), k=8*(l>>5)+j.
// ws layout (unsigned short elems):
// [0,65536)     Gpk: A-frags of (-2LR*G), G=W@W^T (symmetric). frag(kc 0..15, ntg 0..7)
// [65536,98304) Cpk: A-frags of (2LR*W). frag(kc 0..7, ntg 0..7)
// [98304,131072) Opk: A-frags of W^T. frag(kc 0..15, it 0..3)
__global__ void sc_prep(const float* __restrict__ W, unsigned short* __restrict__ ws) {
  const int b = blockIdx.x;
  const int l = threadIdx.x;
  const int r = l & 31, h = l >> 5;
  if (b < 128) {                        // Gpk
    const int kc = b >> 3, ntg = b & 7;
    const int n = ntg * 32 + r;
    const int k0 = kc * 16 + 8 * h;
    float s[8];
    #pragma unroll
    for (int j = 0; j < 8; ++j) s[j] = 0.0f;
    for (int i = 0; i < 128; ++i) {
      const float wn = W[n * 128 + i];
      #pragma unroll
      for (int j = 0; j < 8; ++j) s[j] += W[(k0 + j) * 128 + i] * wn;
    }
    unsigned short* dst = ws + ((unsigned)b * 64u + l) * 8u;
    #pragma unroll
    for (int j = 0; j < 8; ++j) dst[j] = f2bf(-SC_ * s[j]);
  } else if (b < 192) {                 // Cpk
    const int bb = b - 128;
    const int kc = bb >> 3, ntg = bb & 7;
    const int n = ntg * 32 + r;
    const int k0 = kc * 16 + 8 * h;
    unsigned short* dst = ws + 65536u + ((unsigned)bb * 64u + l) * 8u;
    #pragma unroll
    for (int j = 0; j < 8; ++j) dst[j] = f2bf(SC_ * W[n * 128 + k0 + j]);
  } else {                              // Opk
    const int bb = b - 192;
    const int kc = bb >> 2, it = bb & 3;
    const int i = it * 32 + r;
    const int n0 = kc * 16 + 8 * h;
    unsigned short* dst = ws + 98304u + ((unsigned)bb * 64u + l) * 8u;
    #pragma unroll
    for (int j = 0; j < 8; ++j) dst[j] = f2bf(W[(n0 + j) * 128 + i]);
  }
}

// R11: m=64 rows/block (double-work steps). Same 4 waves, n=64/wave; each wave
// computes TWO m-groups -> acc[nt][mg] = 4 x f32x16 (4 natural MFMA chains).
// Rationale: per-step fixed cost (barrier, ds-latency ramp, writeback tail)
// was ~40-60% of each 2400-cyc step and is invariant to m; doubling work/step
// halves fixed cost per FLOP, and halves generation count (c-phase/epilogue/
// global-IO amortize 2x). LDS traffic per FLOP unchanged (broadcast ratio is
// structural). Rotation dropped (R10: +2% only, costs 16 regs).
// Registers: gfr 128 + cp 32 + temps/addr ~30 arch + 64 AGPR acc ~= 254/256.
// NOTE: ONLY __launch_bounds__(256,2) is legal (R2/R4/R7 spill lesson).
// LDS: XB0 [0,33280), XB1 [33280,66560); 64 rows x 520 B stride per buffer.
__global__ __launch_bounds__(256, 2) void sc_fused(
    const float* __restrict__ inp,
    const unsigned short* __restrict__ wsp,
    float* __restrict__ outp)
{
  __shared__ __align__(16) unsigned char lds[66560];

  const int tid = threadIdx.x;
  const int l = tid & 63;
  const int w = tid >> 6;          // 0..3
  const int h = l >> 5;            // 0..1
  const int r31 = l & 31;
  const long row0 = (long)blockIdx.x * 64;

  // B-read base: row = mg*32 + r31, k-col byte = kc*32 + h*16
  const int rBm0 = r31 * 520 + h * 16;           // mg=0
  const int rBm1 = rBm0 + 32 * 520;              // mg=1
  // x-write base: row = mg*32 + r31, n = w*64 + nt*32 + 8q + 4h (+s)
  const int wBm0 = r31 * 520 + w * 128 + h * 8;
  const int wBm1 = wBm0 + 32 * 520;

  // ---- stage 64 input rows -> XB1 (bf16, stride 264) ----
  #pragma unroll
  for (int rep = 0; rep < 8; ++rep) {
    const int flat = rep * 256 + tid;            // 0..2047 float4s
    const int rr = flat >> 5;                    // 0..63
    const int c4 = flat & 31;
    const f32x4 v = *reinterpret_cast<const f32x4*>(inp + (row0 + rr) * 128 + c4 * 4);
    s16x4 p;
    p[0] = (short)f2bf(v[0]); p[1] = (short)f2bf(v[1]);
    p[2] = (short)f2bf(v[2]); p[3] = (short)f2bf(v[3]);
    *reinterpret_cast<s16x4*>(lds + 33280 + rr * 264 + c4 * 8) = p;
  }

  // ---- c-phase A-frags (2LR*W) ----
  s16x8 gfr[32];
  #pragma unroll
  for (int kc = 0; kc < 8; ++kc)
    #pragma unroll
    for (int nt = 0; nt < 2; ++nt)
      gfr[kc * 2 + nt] = *reinterpret_cast<const s16x8*>(
          wsp + 65536u + ((unsigned)(kc * 8 + w * 2 + nt) * 64u + l) * 8u);

  __syncthreads();

  // ---- c = 2LR * W @ in^T, both m-groups; acc[nt][mg] = 4 chains ----
  f32x16 acc[2][2];
  #pragma unroll
  for (int nt = 0; nt < 2; ++nt)
    #pragma unroll
    for (int mg = 0; mg < 2; ++mg)
      #pragma unroll
      for (int e = 0; e < 16; ++e) acc[nt][mg][e] = 0.0f;

  const int ib0 = 33280 + r31 * 264 + h * 16;
  const int ib1 = ib0 + 32 * 264;
  #pragma unroll
  for (int kc = 0; kc < 8; ++kc) {
    const s16x8 b0 = *reinterpret_cast<const s16x8*>(lds + ib0 + kc * 32);
    const s16x8 b1 = *reinterpret_cast<const s16x8*>(lds + ib1 + kc * 32);
    __builtin_amdgcn_s_setprio(1);
    #pragma unroll
    for (int nt = 0; nt < 2; ++nt) {
      acc[nt][0] = __builtin_amdgcn_mfma_f32_32x32x16_bf16(gfr[kc * 2 + nt], b0, acc[nt][0], 0, 0, 0);
      acc[nt][1] = __builtin_amdgcn_mfma_f32_32x32x16_bf16(gfr[kc * 2 + nt], b1, acc[nt][1], 0, 0, 0);
    }
    __builtin_amdgcn_s_setprio(0);
  }

  // c packed bf16x2 (32 regs); x1 = sthr(c) -> XB0; preinit acc = x1 + c_bf
  unsigned cp[32];
  #pragma unroll
  for (int nt = 0; nt < 2; ++nt)
    #pragma unroll
    for (int mg = 0; mg < 2; ++mg)
      #pragma unroll
      for (int j = 0; j < 8; ++j)
        cp[(nt * 2 + mg) * 8 + j] =
            (unsigned)f2bf(acc[nt][mg][2 * j]) |
            ((unsigned)f2bf(acc[nt][mg][2 * j + 1]) << 16);
  #pragma unroll
  for (int nt = 0; nt < 2; ++nt)
    #pragma unroll
    for (int mg = 0; mg < 2; ++mg)
      #pragma unroll
      for (int q = 0; q < 4; ++q) {
        const unsigned pa = cp[(nt * 2 + mg) * 8 + q * 2];
        const unsigned pb = cp[(nt * 2 + mg) * 8 + q * 2 + 1];
        float f0 = sthr(acc[nt][mg][4 * q + 0]);
        float f1 = sthr(acc[nt][mg][4 * q + 1]);
        float f2 = sthr(acc[nt][mg][4 * q + 2]);
        float f3 = sthr(acc[nt][mg][4 * q + 3]);
        s16x4 p;
        p[0] = (short)f2bf(f0); p[1] = (short)f2bf(f1);
        p[2] = (short)f2bf(f2); p[3] = (short)f2bf(f3);
        *reinterpret_cast<s16x4*>(lds + (mg ? wBm1 : wBm0) + nt * 64 + q * 16) = p;
        acc[nt][mg][4 * q + 0] = f0 + bflo(pa); acc[nt][mg][4 * q + 1] = f1 + bfhi(pa);
        acc[nt][mg][4 * q + 2] = f2 + bflo(pb); acc[nt][mg][4 * q + 3] = f3 + bfhi(pb);
      }

  // ---- step A-frags (-2LR*G) ----
  #pragma unroll
  for (int kc = 0; kc < 16; ++kc)
    #pragma unroll
    for (int nt = 0; nt < 2; ++nt)
      gfr[kc * 2 + nt] = *reinterpret_cast<const s16x8*>(
          wsp + ((unsigned)(kc * 8 + w * 2 + nt) * 64u + l) * 8u);

  // ---- one ISTA step (2x work: both m-groups).
  // Entry invariant: acc[nt][mg] = x + c_bf, x in rb buffer.
  auto STEP = [&](const int rb, const int wb) {
    __syncthreads();
    #pragma unroll
    for (int kc = 0; kc < 16; ++kc) {
      const s16x8 b0 = *reinterpret_cast<const s16x8*>(lds + rb + rBm0 + kc * 32);
      const s16x8 b1 = *reinterpret_cast<const s16x8*>(lds + rb + rBm1 + kc * 32);
      __builtin_amdgcn_s_setprio(1);
      #pragma unroll
      for (int nt = 0; nt < 2; ++nt) {
        acc[nt][0] = __builtin_amdgcn_mfma_f32_32x32x16_bf16(gfr[kc * 2 + nt], b0, acc[nt][0], 0, 0, 0);
        acc[nt][1] = __builtin_amdgcn_mfma_f32_32x32x16_bf16(gfr[kc * 2 + nt], b1, acc[nt][1], 0, 0, 0);
      }
      __builtin_amdgcn_s_setprio(0);
    }
    #pragma unroll
    for (int nt = 0; nt < 2; ++nt)
      #pragma unroll
      for (int mg = 0; mg < 2; ++mg)
        #pragma unroll
        for (int q = 0; q < 4; ++q) {
          const unsigned pa = cp[(nt * 2 + mg) * 8 + q * 2];
          const unsigned pb = cp[(nt * 2 + mg) * 8 + q * 2 + 1];
          float f0 = sthr(acc[nt][mg][4 * q + 0]);
          float f1 = sthr(acc[nt][mg][4 * q + 1]);
          float f2 = sthr(acc[nt][mg][4 * q + 2]);
          float f3 = sthr(acc[nt][mg][4 * q + 3]);
          s16x4 p;
          p[0] = (short)f2bf(f0); p[1] = (short)f2bf(f1);
          p[2] = (short)f2bf(f2); p[3] = (short)f2bf(f3);
          *reinterpret_cast<s16x4*>(lds + wb + (mg ? wBm1 : wBm0) + nt * 64 + q * 16) = p;
          acc[nt][mg][4 * q + 0] = f0 + bflo(pa); acc[nt][mg][4 * q + 1] = f1 + bfhi(pa);
          acc[nt][mg][4 * q + 2] = f2 + bflo(pb); acc[nt][mg][4 * q + 3] = f3 + bfhi(pb);
        }
  };

  // 9 steps: x1 in XB0; alternate; x10 lands in XB1
  #pragma unroll 1
  for (int p = 0; p < 4; ++p) {
    STEP(0, 33280);
    STEP(33280, 0);
  }
  STEP(0, 33280);

  // ---- out^T = W^T @ x10^T ; wave w owns out cols [w*32, w*32+32) ----
  __syncthreads();
  #pragma unroll
  for (int kc = 0; kc < 16; ++kc)
    gfr[kc] = *reinterpret_cast<const s16x8*>(
        wsp + 98304u + ((unsigned)(kc * 4 + w) * 64u + l) * 8u);
  f32x16 oacc[2];
  #pragma unroll
  for (int mg = 0; mg < 2; ++mg)
    #pragma unroll
    for (int e = 0; e < 16; ++e) oacc[mg][e] = 0.0f;
  #pragma unroll
  for (int kc = 0; kc < 16; ++kc) {
    const s16x8 b0 = *reinterpret_cast<const s16x8*>(lds + 33280 + rBm0 + kc * 32);
    const s16x8 b1 = *reinterpret_cast<const s16x8*>(lds + 33280 + rBm1 + kc * 32);
    __builtin_amdgcn_s_setprio(1);
    oacc[0] = __builtin_amdgcn_mfma_f32_32x32x16_bf16(gfr[kc], b0, oacc[0], 0, 0, 0);
    oacc[1] = __builtin_amdgcn_mfma_f32_32x32x16_bf16(gfr[kc], b1, oacc[1], 0, 0, 0);
    __builtin_amdgcn_s_setprio(0);
  }
  // stage out f32 -> XB0: row m = mg*32+r31, col i = w*32 + q*8 + 4h (+s)
  const int ob0 = r31 * 520 + w * 128 + h * 16;
  #pragma unroll
  for (int mg = 0; mg < 2; ++mg)
    #pragma unroll
    for (int q = 0; q < 4; ++q) {
      f32x4 p;
      p[0] = oacc[mg][4 * q + 0]; p[1] = oacc[mg][4 * q + 1];
      p[2] = oacc[mg][4 * q + 2]; p[3] = oacc[mg][4 * q + 3];
      *reinterpret_cast<f32x4*>(lds + ob0 + mg * 16640 + q * 32) = p;
    }
  __syncthreads();
  // coalesced copy 64 rows x 128 f32 -> global
  #pragma unroll
  for (int rep = 0; rep < 8; ++rep) {
    const int flat = rep * 256 + tid;
    const int rr = flat >> 5;
    const int c4 = flat & 31;
    const f32x4 v = *reinterpret_cast<const f32x4*>(lds + rr * 520 + c4 * 16);
    *reinterpret_cast<f32x4*>(outp + (row0 + rr) * 128 + c4 * 4) = v;
  }
}

extern "C" void kernel_launch(void* const* d_in, const int* in_sizes, int n_in,
                              void* d_out, int out_size, void* d_ws, size_t ws_size,
                              hipStream_t stream) {
  const float* inp = (const float*)d_in[0];
  const float* W   = (const float*)d_in[1];
  unsigned short* ws = (unsigned short*)d_ws;   // needs 256 KiB
  float* outp = (float*)d_out;
  const int B = in_sizes[0] / 128;              // 131072
  sc_prep<<<256, 64, 0, stream>>>(W, ws);
  sc_fused<<<B / 64, 256, 0, stream>>>(inp, ws, outp);
}